// Round 5
// baseline (189.717 us; speedup 1.0000x reference)
//
#include <hip/hip_runtime.h>
#include <hip/hip_bf16.h>
#include <hip/hip_fp8.h>
#include <stdint.h>

typedef float floatx4 __attribute__((ext_vector_type(4)));

#define B_    4096
#define D_    1024
#define C_    1000
#define CPAD  1024
#define NVALID (B_ + C_)    // 5096 valid columns
#define NBLK  784
#define TAU_INV 10.0f
#define EPS_    1e-8f

__device__ inline unsigned cvt4_fp8(float4 v) {
    __hip_fp8_e4m3 a(v.x), b(v.y), c(v.z), d(v.w);
    return (unsigned)a.__x | ((unsigned)b.__x << 8) | ((unsigned)c.__x << 16) | ((unsigned)d.__x << 24);
}

// ---------------- prep: cvt fp32->fp8, zero accum + pad + done, counts ------
// grid 5111 x 256. Work map (g = global thread):
//   [0, 1048576)         : features cvt, float4 #g -> u32 fp8x4   (4096*1024/4)
//   [1048576, 1304576)   : centers  cvt, float4 #(g-1048576)      (1000*1024/4)
//   [1304576, 1306624)   : zero denom(1024 f4) then possum(1024 f4)
//   [1306624, 1308160)   : zero center pad rows, int4 (24*1024 B = 1536 int4)
//   g == 1308160         : zero done counter
// block 5110 (idle above except done) computes counts[1024] via LDS atomics.
__global__ __launch_bounds__(256) void prep_kernel(
    const float* __restrict__ centers, const float* __restrict__ features,
    const int* __restrict__ targets,
    unsigned* __restrict__ Af8, unsigned* __restrict__ Cf8,
    float* __restrict__ denom, float* __restrict__ possum, int* __restrict__ counts,
    int* __restrict__ done)
{
    const int tid = threadIdx.x;
    const int g = blockIdx.x * 256 + tid;
    if (g < 1048576) {
        Af8[g] = cvt4_fp8(((const float4*)features)[g]);
    } else if (g < 1304576) {
        int i = g - 1048576;
        Cf8[i] = cvt4_fp8(((const float4*)centers)[i]);
    } else if (g < 1306624) {
        int i = g - 1304576;                    // 0..2047
        float4 z = make_float4(0.f, 0.f, 0.f, 0.f);
        if (i < 1024) ((float4*)denom)[i] = z;
        else          ((float4*)possum)[i - 1024] = z;
    } else if (g < 1308160) {
        int i = g - 1306624;                    // 0..1535
        int4 z = make_int4(0, 0, 0, 0);
        ((int4*)((uint8_t*)Cf8 + (size_t)C_ * D_))[i] = z;
    }
    if (g == 1308160) *done = 0;
    if (blockIdx.x == 5110) {
        __shared__ int lc[CPAD];
        #pragma unroll
        for (int j = 0; j < 4; ++j) lc[tid * 4 + j] = 0;
        __syncthreads();
        for (int i = tid; i < B_; i += 256) atomicAdd(&lc[targets[i]], 1);
        __syncthreads();
        int4 o; o.x = lc[tid*4]; o.y = lc[tid*4+1]; o.z = lc[tid*4+2]; o.w = lc[tid*4+3];
        ((int4*)counts)[tid] = o;
    }
}

// ---------------- fused symmetric fp8 GEMM + epilogue + finalize ------------
// Tiles: bid < 528  -> symmetric F.F^T pair (rt <= ct), mirror if rt != ct
//        bid >= 528 -> center tiles: rt = m>>3, col block m&7 of Cf8
// BK = 128 (fp8): ldsA/ldsB 128x128 = 16 KiB each, 8 K-iterations.
// XOR swizzle (16-B chunks, 8 chunks/row): staging lane l reads global chunk
// (l&7)^(l>>3) so slot s of LDS row r holds chunk s^(r&7); fragment ds_read_b64
// then lands <=2 lanes/bank (free). global_load_lds wave-write stays contiguous.
#define GLD_LDS16(g, l) __builtin_amdgcn_global_load_lds( \
    (const __attribute__((address_space(1))) void*)(g),   \
    (__attribute__((address_space(3))) void*)(l), 16, 0, 0)

__global__ __launch_bounds__(256) void gemm_epilogue(
    const uint8_t* __restrict__ Af8,   // [4096][1024] fp8 e4m3
    const uint8_t* __restrict__ Cf8,   // [1024][1024] fp8 (rows >= 1000 zero)
    const int*     __restrict__ counts,
    const int*     __restrict__ targets,
    float* __restrict__ denom, float* __restrict__ possum,
    int* __restrict__ done, float* __restrict__ out)
{
    __shared__ __align__(16) uint8_t ldsA[128 * 128];
    __shared__ __align__(16) uint8_t ldsB[128 * 128];
    __shared__ int lastFlag;
    __shared__ float red[4];

    const int tid  = threadIdx.x;
    const int wave = tid >> 6;
    const int lane = tid & 63;
    const int bid  = blockIdx.x;

    int rt, colTile;
    const uint8_t* Bbase;
    bool mirror;
    if (bid < 528) {
        int idx = bid, r = 0;
        while (idx >= 32 - r) { idx -= 32 - r; ++r; }   // scalar, uniform
        rt = r;
        int ct = r + idx;
        colTile = ct * 128;
        Bbase = Af8 + (size_t)ct * 128 * D_;
        mirror = (ct != rt);
    } else {
        int m = bid - 528;
        rt = m >> 3;
        int cc = m & 7;
        colTile = B_ + cc * 128;
        Bbase = Cf8 + (size_t)cc * 128 * D_;
        mirror = false;
    }
    const int rowTile = rt * 128;

    // staging: instr j of wave w covers LDS rows (j*4+w)*8..+7; lane l -> row
    // +(l>>3), slot l&7, sourcing global chunk (l&7)^(l>>3) (row&7 == l>>3).
    const int srow  = wave * 8 + (lane >> 3);
    const int chunk = (lane & 7) ^ (lane >> 3);
    const uint8_t* gA = Af8   + (size_t)(rowTile + srow) * D_ + chunk * 16;
    const uint8_t* gB = Bbase + (size_t)srow * D_ + chunk * 16;

    floatx4 acc[4][4] = {};

    const int wrow  = (wave >> 1) * 64;
    const int wcolw = (wave & 1) * 64;
    const int fr = lane & 15;
    const int fq = lane >> 4;
    const int frsw = fr & 7;
    int offs[4];
    #pragma unroll
    for (int s = 0; s < 4; ++s)
        offs[s] = (((s * 2 + (fq >> 1)) ^ frsw) * 16) + (fq & 1) * 8;

    for (int k0 = 0; k0 < D_; k0 += 128) {
        if (k0) __syncthreads();
        #pragma unroll
        for (int j = 0; j < 4; ++j) {
            GLD_LDS16(gA + k0 + (size_t)j * 32 * D_, &ldsA[(j * 4 + wave) * 1024]);
            GLD_LDS16(gB + k0 + (size_t)j * 32 * D_, &ldsB[(j * 4 + wave) * 1024]);
        }
        __syncthreads();

        #pragma unroll
        for (int s = 0; s < 4; ++s) {
            long af[4], bfv[4];
            #pragma unroll
            for (int ri = 0; ri < 4; ++ri)
                af[ri] = *(const long*)&ldsA[(wrow + ri * 16 + fr) * 128 + offs[s]];
            #pragma unroll
            for (int ci = 0; ci < 4; ++ci)
                bfv[ci] = *(const long*)&ldsB[(wcolw + ci * 16 + fr) * 128 + offs[s]];
            #pragma unroll
            for (int ri = 0; ri < 4; ++ri)
                #pragma unroll
                for (int ci = 0; ci < 4; ++ci)
                    acc[ri][ci] = __builtin_amdgcn_mfma_f32_16x16x32_fp8_fp8(
                        af[ri], bfv[ci], acc[ri][ci], 0, 0, 0);
        }
    }

    // ---- epilogue ----
    float wv[4]; int tcol[4]; int colg[4];
    #pragma unroll
    for (int ci = 0; ci < 4; ++ci) {
        int cg = colTile + wcolw + ci * 16 + fr;
        colg[ci] = cg;
        int cls = (cg < B_) ? targets[cg] : (cg - B_);
        tcol[ci] = cls;
        wv[ci] = (cg < NVALID) ? 1.f / (float)(counts[cls] + 1) : 0.f;
    }

    float dcol[4] = {0.f, 0.f, 0.f, 0.f};
    float pcol[4] = {0.f, 0.f, 0.f, 0.f};

    #pragma unroll
    for (int ri = 0; ri < 4; ++ri) {
        #pragma unroll
        for (int reg = 0; reg < 4; ++reg) {
            int rowg = rowTile + wrow + ri * 16 + fq * 4 + reg;   // C/D: row=(lane>>4)*4+reg
            int trow = targets[rowg];
            float wr = 1.f / (float)(counts[trow] + 1);
            float dsum = 0.f, psum = 0.f;
            #pragma unroll
            for (int ci = 0; ci < 4; ++ci) {
                float s = acc[ri][ci][reg] * TAU_INV;
                float e = __expf(s);
                dsum += wv[ci] * e;
                bool pos = (tcol[ci] == trow) && (colg[ci] != rowg);
                float gterm = pos ? (s + log1pf(EPS_ * __expf(-s))) : 0.f;   // log(exp(s)+eps)
                psum += gterm;
                if (mirror) { dcol[ci] += wr * e; pcol[ci] += gterm; }
            }
            #pragma unroll
            for (int m = 1; m < 16; m <<= 1) {
                dsum += __shfl_xor(dsum, m, 64);
                psum += __shfl_xor(psum, m, 64);
            }
            if (fr == 0) {
                atomicAdd(&denom[rowg],  dsum);
                atomicAdd(&possum[rowg], psum);
            }
        }
    }

    if (mirror) {
        #pragma unroll
        for (int ci = 0; ci < 4; ++ci) {
            float d = dcol[ci], p = pcol[ci];
            d += __shfl_xor(d, 16, 64); d += __shfl_xor(d, 32, 64);
            p += __shfl_xor(p, 16, 64); p += __shfl_xor(p, 32, 64);
            if (fq == 0) {
                atomicAdd(&denom[colg[ci]],  d);
                atomicAdd(&possum[colg[ci]], p);
            }
        }
    }

    // ---- completion counter: last block computes the mean loss ----
    __syncthreads();                       // all block atomics issued & drained
    if (tid == 0) {
        __threadfence();                   // device-scope release
        int old = __hip_atomic_fetch_add(done, 1, __ATOMIC_ACQ_REL, __HIP_MEMORY_SCOPE_AGENT);
        lastFlag = (old == NBLK - 1);
    }
    __syncthreads();
    if (lastFlag) {
        float local = 0.f;
        for (int i = tid; i < B_; i += 256) {
            float dn = __hip_atomic_load(&denom[i],  __ATOMIC_RELAXED, __HIP_MEMORY_SCOPE_AGENT);
            float ps = __hip_atomic_load(&possum[i], __ATOMIC_RELAXED, __HIP_MEMORY_SCOPE_AGENT);
            float npos = (float)counts[targets[i]];
            local += logf(dn + EPS_) - ps / npos;
        }
        #pragma unroll
        for (int m = 1; m < 64; m <<= 1) local += __shfl_xor(local, m, 64);
        if (lane == 0) red[wave] = local;
        __syncthreads();
        if (tid == 0) out[0] = (red[0] + red[1] + red[2] + red[3]) * (1.f / (float)B_);
    }
}

extern "C" void kernel_launch(void* const* d_in, const int* in_sizes, int n_in,
                              void* d_out, int out_size, void* d_ws, size_t ws_size,
                              hipStream_t stream) {
    const float* centers  = (const float*)d_in[0];   // [1000][1024]
    const float* features = (const float*)d_in[1];   // [4096][1024]
    const int*   targets  = (const int*)d_in[2];     // [4096]
    float* out = (float*)d_out;

    char* ws = (char*)d_ws;
    unsigned* Af8  = (unsigned*)(ws);                      // 4 MiB fp8
    unsigned* Cf8  = (unsigned*)(ws + 4194304);            // 1 MiB fp8 (rows 1000..1023 zeroed)
    int*    counts = (int*)   (ws + 5242880);              // 1024 i32
    float*  denom  = (float*) (ws + 5246976);              // 4096 f32
    float*  possum = (float*) (ws + 5263360);              // 4096 f32
    int*    done   = (int*)   (ws + 5279744);              // 1 i32

    hipLaunchKernelGGL(prep_kernel, dim3(5111), dim3(256), 0, stream,
                       centers, features, targets, Af8, Cf8, denom, possum, counts, done);
    hipLaunchKernelGGL(gemm_epilogue, dim3(NBLK), dim3(256), 0, stream,
                       (const uint8_t*)Af8, (const uint8_t*)Cf8, counts, targets,
                       denom, possum, done, out);
}

// Round 6
// 165.154 us; speedup vs baseline: 1.1487x; 1.1487x over previous
//
#include <hip/hip_runtime.h>
#include <hip/hip_bf16.h>
#include <hip/hip_fp8.h>
#include <stdint.h>

typedef float floatx4 __attribute__((ext_vector_type(4)));

#define B_    4096
#define D_    1024
#define C_    1000
#define CPAD  1024
#define NVALID (B_ + C_)    // 5096 valid columns
#define NBLK  784
#define TAU_INV 10.0f
#define EPS_    1e-8f

__device__ inline unsigned cvt4_fp8(float4 v) {
    __hip_fp8_e4m3 a(v.x), b(v.y), c(v.z), d(v.w);
    return (unsigned)a.__x | ((unsigned)b.__x << 8) | ((unsigned)c.__x << 16) | ((unsigned)d.__x << 24);
}

// ---------------- prep: cvt fp32->fp8, zero accum + pad + done, counts ------
// grid 5111 x 256. Work map (g = global thread):
//   [0, 1048576)         : features cvt, float4 #g -> u32 fp8x4   (4096*1024/4)
//   [1048576, 1304576)   : centers  cvt, float4 #(g-1048576)      (1000*1024/4)
//   [1304576, 1306624)   : zero denom(1024 f4) then possum(1024 f4)
//   [1306624, 1308160)   : zero center pad rows, int4 (24*1024 B = 1536 int4)
//   g == 1308160         : zero done counter
// block 5110 (idle above except done) computes counts[1024] via LDS atomics.
__global__ __launch_bounds__(256) void prep_kernel(
    const float* __restrict__ centers, const float* __restrict__ features,
    const int* __restrict__ targets,
    unsigned* __restrict__ Af8, unsigned* __restrict__ Cf8,
    float* __restrict__ denom, float* __restrict__ possum, int* __restrict__ counts,
    int* __restrict__ done)
{
    const int tid = threadIdx.x;
    const int g = blockIdx.x * 256 + tid;
    if (g < 1048576) {
        Af8[g] = cvt4_fp8(((const float4*)features)[g]);
    } else if (g < 1304576) {
        int i = g - 1048576;
        Cf8[i] = cvt4_fp8(((const float4*)centers)[i]);
    } else if (g < 1306624) {
        int i = g - 1304576;                    // 0..2047
        float4 z = make_float4(0.f, 0.f, 0.f, 0.f);
        if (i < 1024) ((float4*)denom)[i] = z;
        else          ((float4*)possum)[i - 1024] = z;
    } else if (g < 1308160) {
        int i = g - 1306624;                    // 0..1535
        int4 z = make_int4(0, 0, 0, 0);
        ((int4*)((uint8_t*)Cf8 + (size_t)C_ * D_))[i] = z;
    }
    if (g == 1308160) *done = 0;
    if (blockIdx.x == 5110) {
        __shared__ int lc[CPAD];
        #pragma unroll
        for (int j = 0; j < 4; ++j) lc[tid * 4 + j] = 0;
        __syncthreads();
        for (int i = tid; i < B_; i += 256) atomicAdd(&lc[targets[i]], 1);
        __syncthreads();
        int4 o; o.x = lc[tid*4]; o.y = lc[tid*4+1]; o.z = lc[tid*4+2]; o.w = lc[tid*4+3];
        ((int4*)counts)[tid] = o;
    }
}

// ---------------- fused symmetric fp8 GEMM + epilogue + finalize ------------
// Tiles: bid < 528  -> symmetric F.F^T pair (rt <= ct), mirror if rt != ct
//        bid >= 528 -> center tiles: rt = m>>3, col block m&7 of Cf8
// BK = 64 (fp8): ldsA/ldsB 128x64 = 8 KiB each, 16 K-iterations (R4-proven).
// __launch_bounds__(256,3): unified-reg cap 170 (64 acc + ~106 arch) -> 3 blk/CU.
#define GLD_LDS16(g, l) __builtin_amdgcn_global_load_lds( \
    (const __attribute__((address_space(1))) void*)(g),   \
    (__attribute__((address_space(3))) void*)(l), 16, 0, 0)

__global__ __launch_bounds__(256, 3) void gemm_epilogue(
    const uint8_t* __restrict__ Af8,   // [4096][1024] fp8 e4m3
    const uint8_t* __restrict__ Cf8,   // [1024][1024] fp8 (rows >= 1000 zero)
    const int*     __restrict__ counts,
    const int*     __restrict__ targets,
    float* __restrict__ denom, float* __restrict__ possum,
    int* __restrict__ done, float* __restrict__ out)
{
    __shared__ __align__(16) uint8_t ldsA[128 * 64];
    __shared__ __align__(16) uint8_t ldsB[128 * 64];
    __shared__ int lastFlag;
    __shared__ float red[4];

    const int tid  = threadIdx.x;
    const int wave = tid >> 6;
    const int lane = tid & 63;
    const int bid  = blockIdx.x;

    int rt, colTile;
    const uint8_t* Bbase;
    bool mirror;
    if (bid < 528) {
        int idx = bid, r = 0;
        while (idx >= 32 - r) { idx -= 32 - r; ++r; }   // scalar, uniform
        rt = r;
        int ct = r + idx;
        colTile = ct * 128;
        Bbase = Af8 + (size_t)ct * 128 * D_;
        mirror = (ct != rt);
    } else {
        int m = bid - 528;
        rt = m >> 3;
        int cc = m & 7;
        colTile = B_ + cc * 128;
        Bbase = Cf8 + (size_t)cc * 128 * D_;
        mirror = false;
    }
    const int rowTile = rt * 128;

    // staging (R4-proven): 2 instrs per matrix; instr j covers LDS rows
    // (wave + 4j)*16..+15; lane l -> row +(l>>2), chunk (l&3) XOR-permuted.
    const int r0 = wave * 16 + (lane >> 2);
    const int r1 = r0 + 64;
    const int gc0 = ((lane & 3) ^ ((r0 >> 1) & 3)) * 16;
    const int gc1 = ((lane & 3) ^ ((r1 >> 1) & 3)) * 16;
    const uint8_t* gA0 = Af8 + (size_t)(rowTile + r0) * D_ + gc0;
    const uint8_t* gA1 = Af8 + (size_t)(rowTile + r1) * D_ + gc1;
    const uint8_t* gB0 = Bbase + (size_t)r0 * D_ + gc0;
    const uint8_t* gB1 = Bbase + (size_t)r1 * D_ + gc1;
    uint8_t* lA0 = &ldsA[wave * 1024];
    uint8_t* lA1 = &ldsA[(wave + 4) * 1024];
    uint8_t* lB0 = &ldsB[wave * 1024];
    uint8_t* lB1 = &ldsB[(wave + 4) * 1024];

    floatx4 acc[4][4] = {};

    const int wrow  = (wave >> 1) * 64;
    const int wcolw = (wave & 1) * 64;
    const int fr = lane & 15;
    const int fq = lane >> 4;
    const int sw = (fr >> 1) & 3;
    const int off_s0 = (((fq >> 1) ^ sw) * 16) + (fq & 1) * 8;          // s=0: kchunk = fq>>1
    const int off_s1 = (((2 + (fq >> 1)) ^ sw) * 16) + (fq & 1) * 8;    // s=1: kchunk = 2 + fq>>1

    for (int k0 = 0; k0 < D_; k0 += 64) {
        if (k0) __syncthreads();
        GLD_LDS16(gA0 + k0, lA0);
        GLD_LDS16(gA1 + k0, lA1);
        GLD_LDS16(gB0 + k0, lB0);
        GLD_LDS16(gB1 + k0, lB1);
        __syncthreads();

        #pragma unroll
        for (int s = 0; s < 2; ++s) {
            const int off = s ? off_s1 : off_s0;
            long af[4], bfv[4];
            #pragma unroll
            for (int ri = 0; ri < 4; ++ri)
                af[ri] = *(const long*)&ldsA[(wrow + ri * 16 + fr) * 64 + off];
            #pragma unroll
            for (int ci = 0; ci < 4; ++ci)
                bfv[ci] = *(const long*)&ldsB[(wcolw + ci * 16 + fr) * 64 + off];
            #pragma unroll
            for (int ri = 0; ri < 4; ++ri)
                #pragma unroll
                for (int ci = 0; ci < 4; ++ci)
                    acc[ri][ci] = __builtin_amdgcn_mfma_f32_16x16x32_fp8_fp8(
                        af[ri], bfv[ci], acc[ri][ci], 0, 0, 0);
        }
    }

    // ---- epilogue pass 1: row-side (all tiles) ----
    float wv[4]; int tcol[4]; int colg[4];
    #pragma unroll
    for (int ci = 0; ci < 4; ++ci) {
        int cg = colTile + wcolw + ci * 16 + fr;
        colg[ci] = cg;
        int cls = (cg < B_) ? targets[cg] : (cg - B_);
        tcol[ci] = cls;
        wv[ci] = (cg < NVALID) ? 1.f / (float)(counts[cls] + 1) : 0.f;
    }

    #pragma unroll
    for (int ri = 0; ri < 4; ++ri) {
        #pragma unroll
        for (int reg = 0; reg < 4; ++reg) {
            int rowg = rowTile + wrow + ri * 16 + fq * 4 + reg;   // C/D: row=(lane>>4)*4+reg
            int trow = targets[rowg];
            float dsum = 0.f, psum = 0.f;
            #pragma unroll
            for (int ci = 0; ci < 4; ++ci) {
                float s = acc[ri][ci][reg] * TAU_INV;
                float e = __expf(s);
                dsum += wv[ci] * e;
                bool pos = (tcol[ci] == trow) && (colg[ci] != rowg);
                psum += pos ? (s + log1pf(EPS_ * __expf(-s))) : 0.f;   // log(exp(s)+eps)
            }
            #pragma unroll
            for (int m = 1; m < 16; m <<= 1) {
                dsum += __shfl_xor(dsum, m, 64);
                psum += __shfl_xor(psum, m, 64);
            }
            if (fr == 0) {
                atomicAdd(&denom[rowg],  dsum);
                atomicAdd(&possum[rowg], psum);
            }
        }
    }

    // ---- epilogue pass 2: column-side (mirror tiles only) ----
    // Recompute exp from acc: ~64 extra __expf per thread, once per block —
    // trades ~8 long-lived VGPRs for trivial VALU.
    if (mirror) {
        #pragma unroll
        for (int ci = 0; ci < 4; ++ci) {
            float d = 0.f, p = 0.f;
            #pragma unroll
            for (int ri = 0; ri < 4; ++ri) {
                #pragma unroll
                for (int reg = 0; reg < 4; ++reg) {
                    int rowg = rowTile + wrow + ri * 16 + fq * 4 + reg;
                    int trow = targets[rowg];
                    float wr = 1.f / (float)(counts[trow] + 1);
                    float s = acc[ri][ci][reg] * TAU_INV;
                    float e = __expf(s);
                    d += wr * e;
                    bool pos = (tcol[ci] == trow) && (colg[ci] != rowg);
                    p += pos ? (s + log1pf(EPS_ * __expf(-s))) : 0.f;
                }
            }
            d += __shfl_xor(d, 16, 64); d += __shfl_xor(d, 32, 64);
            p += __shfl_xor(p, 16, 64); p += __shfl_xor(p, 32, 64);
            if (fq == 0) {
                atomicAdd(&denom[colg[ci]],  d);
                atomicAdd(&possum[colg[ci]], p);
            }
        }
    }

    // ---- completion counter: last block computes the mean loss ----
    __syncthreads();
    if (tid == 0) {
        __threadfence();                   // device-scope release
        int old = __hip_atomic_fetch_add(done, 1, __ATOMIC_ACQ_REL, __HIP_MEMORY_SCOPE_AGENT);
        lastFlag = (old == NBLK - 1);
    }
    __syncthreads();
    if (lastFlag) {
        float local = 0.f;
        for (int i = tid; i < B_; i += 256) {
            float dn = __hip_atomic_load(&denom[i],  __ATOMIC_RELAXED, __HIP_MEMORY_SCOPE_AGENT);
            float ps = __hip_atomic_load(&possum[i], __ATOMIC_RELAXED, __HIP_MEMORY_SCOPE_AGENT);
            float npos = (float)counts[targets[i]];
            local += logf(dn + EPS_) - ps / npos;
        }
        #pragma unroll
        for (int m = 1; m < 64; m <<= 1) local += __shfl_xor(local, m, 64);
        if (lane == 0) red[wave] = local;
        __syncthreads();
        if (tid == 0) out[0] = (red[0] + red[1] + red[2] + red[3]) * (1.f / (float)B_);
    }
}

extern "C" void kernel_launch(void* const* d_in, const int* in_sizes, int n_in,
                              void* d_out, int out_size, void* d_ws, size_t ws_size,
                              hipStream_t stream) {
    const float* centers  = (const float*)d_in[0];   // [1000][1024]
    const float* features = (const float*)d_in[1];   // [4096][1024]
    const int*   targets  = (const int*)d_in[2];     // [4096]
    float* out = (float*)d_out;

    char* ws = (char*)d_ws;
    unsigned* Af8  = (unsigned*)(ws);                      // 4 MiB fp8
    unsigned* Cf8  = (unsigned*)(ws + 4194304);            // 1 MiB fp8 (rows 1000..1023 zeroed)
    int*    counts = (int*)   (ws + 5242880);              // 1024 i32
    float*  denom  = (float*) (ws + 5246976);              // 4096 f32
    float*  possum = (float*) (ws + 5263360);              // 4096 f32
    int*    done   = (int*)   (ws + 5279744);              // 1 i32

    hipLaunchKernelGGL(prep_kernel, dim3(5111), dim3(256), 0, stream,
                       centers, features, targets, Af8, Cf8, denom, possum, counts, done);
    hipLaunchKernelGGL(gemm_epilogue, dim3(NBLK), dim3(256), 0, stream,
                       (const uint8_t*)Af8, (const uint8_t*)Cf8, counts, targets,
                       denom, possum, done, out);
}